// Round 1
// baseline (429.296 us; speedup 1.0000x reference)
//
#include <hip/hip_runtime.h>

typedef __attribute__((ext_vector_type(4))) float f32x4;
typedef __attribute__((ext_vector_type(8))) short s16x8;

// ---------- exact fp8 e4m3fn round-trip (RNE), matching ml_dtypes/jax ----------
__device__ __forceinline__ float qdq_e4m3(float v) {
    unsigned int u = __float_as_uint(v);
    unsigned int s = u & 0x80000000u;
    unsigned int a = u & 0x7fffffffu;
    if (a >= 0x3C800000u) {                 // |v| >= 2^-6 : normal e4m3 range
        // round mantissa to 3 bits, RNE (carry into exponent handled by add)
        unsigned int r = a + 0x7FFFFu + ((a >> 20) & 1u);
        r &= 0xFFF00000u;
        if (r > 0x43E00000u) r = 0x43E00000u;  // saturate at 448 (can't trigger here)
        return __uint_as_float(s | r);
    } else {                                 // subnormal: grid of 2^-9
        float f = __uint_as_float(a);
        float m = rintf(f * 512.0f) * (1.0f / 512.0f);
        return __uint_as_float(s | __float_as_uint(m));
    }
}

__device__ __forceinline__ unsigned short f32_to_bf16_bits(float f) {
    unsigned int u = __float_as_uint(f);
    u += 0x7FFFu + ((u >> 16) & 1u);        // RNE
    return (unsigned short)(u >> 16);
}

// ---------- quantize x: per-row 1x64 tiles; 16 lanes per tile, float4/lane ----------
__global__ __launch_bounds__(256) void quant_x_kernel(const float* __restrict__ x,
                                                      unsigned short* __restrict__ xq,
                                                      long long n4) {  // # of float4 chunks
    long long g = (long long)blockIdx.x * 256 + threadIdx.x;
    if (g >= n4) return;
    f32x4 v = ((const f32x4*)x)[g];
    float a = fmaxf(fmaxf(fabsf(v.x), fabsf(v.y)), fmaxf(fabsf(v.z), fabsf(v.w)));
    // reduce amax within the 16-lane group (one 64-elem tile)
    a = fmaxf(a, __shfl_xor(a, 1));
    a = fmaxf(a, __shfl_xor(a, 2));
    a = fmaxf(a, __shfl_xor(a, 4));
    a = fmaxf(a, __shfl_xor(a, 8));
    float scale = fmaxf(a, 1e-12f) / 448.0f;
    ushort4 o;
    o.x = f32_to_bf16_bits(qdq_e4m3(v.x / scale) * scale);
    o.y = f32_to_bf16_bits(qdq_e4m3(v.y / scale) * scale);
    o.z = f32_to_bf16_bits(qdq_e4m3(v.z / scale) * scale);
    o.w = f32_to_bf16_bits(qdq_e4m3(v.w / scale) * scale);
    ((ushort4*)xq)[g] = o;
}

// ---------- quantize w: 64x64 blocks; one 256-thread block per weight block ----------
__global__ __launch_bounds__(256) void quant_w_kernel(const float* __restrict__ w,
                                                      unsigned short* __restrict__ wq,
                                                      int N, int K) {
    const int nb = blockIdx.y, kb = blockIdx.x;
    const int t = threadIdx.x;
    const int rgrp = t >> 4;        // 0..15
    const int cchk = t & 15;        // col chunk: 4 floats
    f32x4 v[4];
    float a = 0.0f;
#pragma unroll
    for (int i = 0; i < 4; ++i) {
        int row = nb * 64 + rgrp + i * 16;
        v[i] = *(const f32x4*)(w + (size_t)row * K + kb * 64 + cchk * 4);
        a = fmaxf(a, fmaxf(fmaxf(fabsf(v[i].x), fabsf(v[i].y)),
                           fmaxf(fabsf(v[i].z), fabsf(v[i].w))));
    }
#pragma unroll
    for (int off = 1; off < 64; off <<= 1) a = fmaxf(a, __shfl_xor(a, off));
    __shared__ float sm[4];
    if ((t & 63) == 0) sm[t >> 6] = a;
    __syncthreads();
    a = fmaxf(fmaxf(sm[0], sm[1]), fmaxf(sm[2], sm[3]));
    float scale = fmaxf(a, 1e-12f) / 448.0f;
#pragma unroll
    for (int i = 0; i < 4; ++i) {
        int row = nb * 64 + rgrp + i * 16;
        ushort4 o;
        o.x = f32_to_bf16_bits(qdq_e4m3(v[i].x / scale) * scale);
        o.y = f32_to_bf16_bits(qdq_e4m3(v[i].y / scale) * scale);
        o.z = f32_to_bf16_bits(qdq_e4m3(v[i].z / scale) * scale);
        o.w = f32_to_bf16_bits(qdq_e4m3(v[i].w / scale) * scale);
        *(ushort4*)(wq + (size_t)row * K + kb * 64 + cchk * 4) = o;
    }
}

// ---------- bf16 GEMM, A[M,K] x B[N,K]^T, m97 structure ----------
// 128x128 tile, 4 waves (2x2), BK=32, global_load_lds width 16, 2-barrier loop.
__global__ __launch_bounds__(256) void gemm_bt(const unsigned short* __restrict__ A,
                                               const unsigned short* __restrict__ B,
                                               const float* __restrict__ bias,
                                               float* __restrict__ C,
                                               int M, int N, int K) {
    __shared__ unsigned short Al[128 * 32];
    __shared__ unsigned short Bl[128 * 32];
    const int tid  = threadIdx.x;
    const int wid  = tid >> 6;
    const int lane = tid & 63;
    const int wr = wid >> 1, wc = wid & 1;
    const int lrow = lane & 15;
    const int kh   = lane >> 4;           // k-half group: k = kh*8 .. kh*8+7
    const int sidx0 = wid * 2;            // this wave's two staging slots

    const unsigned short* gA = A + (size_t)blockIdx.y * 128 * K;
    const unsigned short* gB = B + (size_t)blockIdx.x * 128 * K;

    f32x4 acc[4][4] = {};

    for (int k0 = 0; k0 < K; k0 += 32) {
#pragma unroll
        for (int i = 0; i < 2; ++i) {
            int idx = (sidx0 + i) * 64 + lane;   // 0..511
            int row = idx >> 2;
            int chk = idx & 3;
            __builtin_amdgcn_global_load_lds(
                (__attribute__((address_space(1))) void*)(gA + (size_t)row * K + k0 + chk * 8),
                (__attribute__((address_space(3))) void*)(Al + (sidx0 + i) * 512),
                16, 0, 0);
            __builtin_amdgcn_global_load_lds(
                (__attribute__((address_space(1))) void*)(gB + (size_t)row * K + k0 + chk * 8),
                (__attribute__((address_space(3))) void*)(Bl + (sidx0 + i) * 512),
                16, 0, 0);
        }
        __syncthreads();   // drains vmcnt: staged data visible

        s16x8 af[4], bfr[4];
#pragma unroll
        for (int m = 0; m < 4; ++m)
            af[m] = *(const s16x8*)(Al + (wr * 64 + m * 16 + lrow) * 32 + kh * 8);
#pragma unroll
        for (int n = 0; n < 4; ++n)
            bfr[n] = *(const s16x8*)(Bl + (wc * 64 + n * 16 + lrow) * 32 + kh * 8);
#pragma unroll
        for (int m = 0; m < 4; ++m)
#pragma unroll
            for (int n = 0; n < 4; ++n)
                acc[m][n] = __builtin_amdgcn_mfma_f32_16x16x32_bf16(af[m], bfr[n], acc[m][n], 0, 0, 0);
        __syncthreads();   // all reads done before next stage overwrites
    }

    // epilogue: C/D layout col=lane&15, row=(lane>>4)*4+j  [m89 verified]
    const int gcol0 = blockIdx.x * 128 + wc * 64 + lrow;
    const int grow0 = blockIdx.y * 128 + wr * 64 + (lane >> 4) * 4;
#pragma unroll
    for (int n = 0; n < 4; ++n) {
        float bv = bias[gcol0 + n * 16];
#pragma unroll
        for (int m = 0; m < 4; ++m) {
#pragma unroll
            for (int j = 0; j < 4; ++j) {
                unsigned short b = f32_to_bf16_bits(acc[m][n][j]);
                float vb = __uint_as_float(((unsigned int)b) << 16) + bv;
                C[(size_t)(grow0 + m * 16 + j) * N + gcol0 + n * 16] = vb;
            }
        }
    }
}

extern "C" void kernel_launch(void* const* d_in, const int* in_sizes, int n_in,
                              void* d_out, int out_size, void* d_ws, size_t ws_size,
                              hipStream_t stream) {
    const float* x    = (const float*)d_in[0];
    const float* w    = (const float*)d_in[1];
    const float* bias = (const float*)d_in[2];
    float* out = (float*)d_out;

    const int N = in_sizes[2];                       // 4096
    const long long KL = (long long)in_sizes[1] / N; // 4096
    const int K = (int)KL;
    const int M = (int)((long long)in_sizes[0] / KL); // 8192

    // workspace: xq [M,K] bf16 (64 MB) + wq [N,K] bf16 (32 MB)
    unsigned short* xq = (unsigned short*)d_ws;
    unsigned short* wq = xq + (size_t)M * K;

    long long n4 = (long long)M * K / 4;   // float4 chunks (16 lanes per 64-tile)
    quant_x_kernel<<<(unsigned)((n4 + 255) / 256), 256, 0, stream>>>(x, xq, n4);

    dim3 gw(K / 64, N / 64);
    quant_w_kernel<<<gw, 256, 0, stream>>>(w, wq, N, K);

    dim3 gg(N / 128, M / 128);
    gemm_bt<<<gg, 256, 0, stream>>>(xq, wq, bias, out, M, N, K);
}

// Round 3
// 371.689 us; speedup vs baseline: 1.1550x; 1.1550x over previous
//
#include <hip/hip_runtime.h>

typedef __attribute__((ext_vector_type(4))) float f32x4;
typedef __attribute__((ext_vector_type(8))) short s16x8;

// ---------- exact fp8 e4m3fn round-trip (RNE), matching ml_dtypes/jax ----------
__device__ __forceinline__ float qdq_e4m3(float v) {
    unsigned int u = __float_as_uint(v);
    unsigned int s = u & 0x80000000u;
    unsigned int a = u & 0x7fffffffu;
    if (a >= 0x3C800000u) {                 // |v| >= 2^-6 : normal e4m3 range
        unsigned int r = a + 0x7FFFFu + ((a >> 20) & 1u);
        r &= 0xFFF00000u;
        if (r > 0x43E00000u) r = 0x43E00000u;  // saturate at 448
        return __uint_as_float(s | r);
    } else {                                 // subnormal: grid of 2^-9
        float f = __uint_as_float(a);
        float m = rintf(f * 512.0f) * (1.0f / 512.0f);
        return __uint_as_float(s | __float_as_uint(m));
    }
}

__device__ __forceinline__ unsigned short f32_to_bf16_bits(float f) {
    unsigned int u = __float_as_uint(f);
    u += 0x7FFFu + ((u >> 16) & 1u);        // RNE
    return (unsigned short)(u >> 16);
}

// ---------- quantize x: per-row 1x64 tiles; 16 lanes per tile, float4/lane ----------
__global__ __launch_bounds__(256) void quant_x_kernel(const float* __restrict__ x,
                                                      unsigned short* __restrict__ xq,
                                                      long long n4) {
    long long g = (long long)blockIdx.x * 256 + threadIdx.x;
    if (g >= n4) return;
    f32x4 v = ((const f32x4*)x)[g];
    float a = fmaxf(fmaxf(fabsf(v.x), fabsf(v.y)), fmaxf(fabsf(v.z), fabsf(v.w)));
    a = fmaxf(a, __shfl_xor(a, 1));
    a = fmaxf(a, __shfl_xor(a, 2));
    a = fmaxf(a, __shfl_xor(a, 4));
    a = fmaxf(a, __shfl_xor(a, 8));
    float scale = fmaxf(a, 1e-12f) / 448.0f;
    ushort4 o;
    o.x = f32_to_bf16_bits(qdq_e4m3(v.x / scale) * scale);
    o.y = f32_to_bf16_bits(qdq_e4m3(v.y / scale) * scale);
    o.z = f32_to_bf16_bits(qdq_e4m3(v.z / scale) * scale);
    o.w = f32_to_bf16_bits(qdq_e4m3(v.w / scale) * scale);
    ((ushort4*)xq)[g] = o;
}

// ---------- quantize w: 64x64 blocks; one 256-thread block per weight block ----------
__global__ __launch_bounds__(256) void quant_w_kernel(const float* __restrict__ w,
                                                      unsigned short* __restrict__ wq,
                                                      int N, int K) {
    const int nb = blockIdx.y, kb = blockIdx.x;
    const int t = threadIdx.x;
    const int rgrp = t >> 4;
    const int cchk = t & 15;
    f32x4 v[4];
    float a = 0.0f;
#pragma unroll
    for (int i = 0; i < 4; ++i) {
        int row = nb * 64 + rgrp + i * 16;
        v[i] = *(const f32x4*)(w + (size_t)row * K + kb * 64 + cchk * 4);
        a = fmaxf(a, fmaxf(fmaxf(fabsf(v[i].x), fabsf(v[i].y)),
                           fmaxf(fabsf(v[i].z), fabsf(v[i].w))));
    }
#pragma unroll
    for (int off = 1; off < 64; off <<= 1) a = fmaxf(a, __shfl_xor(a, off));
    __shared__ float sm[4];
    if ((t & 63) == 0) sm[t >> 6] = a;
    __syncthreads();
    a = fmaxf(fmaxf(sm[0], sm[1]), fmaxf(sm[2], sm[3]));
    float scale = fmaxf(a, 1e-12f) / 448.0f;
#pragma unroll
    for (int i = 0; i < 4; ++i) {
        int row = nb * 64 + rgrp + i * 16;
        ushort4 o;
        o.x = f32_to_bf16_bits(qdq_e4m3(v[i].x / scale) * scale);
        o.y = f32_to_bf16_bits(qdq_e4m3(v[i].y / scale) * scale);
        o.z = f32_to_bf16_bits(qdq_e4m3(v[i].z / scale) * scale);
        o.w = f32_to_bf16_bits(qdq_e4m3(v[i].w / scale) * scale);
        *(ushort4*)(wq + (size_t)row * K + kb * 64 + cchk * 4) = o;
    }
}

// ---------- 256x256 8-phase bf16 GEMM, A[M,K] x B[N,K]^T ----------
// BM=BN=256, BK=64, 8 waves (2Mx4N), dbuf LDS w/ XOR-swizzle, counted vmcnt,
// setprio around MFMA clusters, XCD-aware block swizzle.
// Swizzle: LDS[r][chunk j] = G[r][chunk j ^ (r&7)]  (chunk = 16B unit, 8/row)
//   write side: linear LDS dest, global col chunk pre-swizzled with lane>>3
//   read side:  chunk(c) at LDS col ((c ^ (r&7)) << 4); c=kh -> cLo, c=kh+4 -> cLo^64
#define GLDS(srcp, ldsp) __builtin_amdgcn_global_load_lds( \
    (__attribute__((address_space(1))) void*)(srcp),       \
    (__attribute__((address_space(3))) void*)(ldsp), 16, 0, 0)

__global__ __launch_bounds__(512, 2) void gemm8p(const unsigned short* __restrict__ A,
                                                 const unsigned short* __restrict__ B,
                                                 const float* __restrict__ bias,
                                                 float* __restrict__ C,
                                                 int M, int N, int K) {
    __shared__ unsigned short Al[2][256 * 64];
    __shared__ unsigned short Bl[2][256 * 64];
    const int tid = threadIdx.x;
    const int wid = tid >> 6;
    const int lane = tid & 63;
    const int wm = wid >> 2, wn = wid & 3;
    const int lrow = lane & 15, kh = lane >> 4;

    // XCD-aware bijective swizzle (nwg % 8 == 0 here: 512)
    const int nbx = N >> 8;
    const int nwg = (M >> 8) * nbx;
    const int bid = blockIdx.x;
    const int swz = (bid & 7) * (nwg >> 3) + (bid >> 3);
    const int tm = swz / nbx, tn = swz % nbx;

    const unsigned short* gA = A + (size_t)tm * 256 * K;
    const unsigned short* gB = B + (size_t)tn * 256 * K;

    // staging: LDS dest linear (seg*1024 + lane*16); global src col pre-swizzled
    const int srow = lane >> 3;                       // row within 8-row segment
    const int scolb = ((lane & 7) ^ srow) << 4;       // swizzled byte col [0,128)

    // ds_read side: byte col for k-chunk kh is (kh ^ (r&7))<<4; r&7 == lane&7
    const int cLo = ((kh ^ (lane & 7)) << 4);         // k = kh*8 .. kh*8+7
    const int cHi = cLo ^ 64;                         // k = 32 + kh*8 ..  (chunk kh+4 = kh^4)
    const char* pA0 = (const char*)&Al[0][0] + ((wm << 7) + lrow) * 128;
    const char* pB0 = (const char*)&Bl[0][0] + ((wn << 6) + lrow) * 128;

    const int NT = K >> 6;

    f32x4 acc[8][4];
#pragma unroll
    for (int m = 0; m < 8; ++m)
#pragma unroll
        for (int n = 0; n < 4; ++n) acc[m][n] = (f32x4){0.f, 0.f, 0.f, 0.f};

    s16x8 af[4][2], bf[2][2];

    auto STG = [&](int p, int t, int bufn) {
        const int seg = p * 8 + wid;                  // wave-uniform
        const int row = seg * 8 + srow;
        GLDS((const char*)gA + ((size_t)row * K + (size_t)t * 64) * 2 + scolb,
             (char*)&Al[bufn][0] + seg * 1024);
        GLDS((const char*)gB + ((size_t)row * K + (size_t)t * 64) * 2 + scolb,
             (char*)&Bl[bufn][0] + seg * 1024);
    };

    // prologue: stage tile 0 -> buf 0 (8 loads/wave)
#pragma unroll
    for (int p = 0; p < 4; ++p) STG(p, 0, 0);

    auto TILE = [&](int buf, int tnx) {
        const int nbuf = buf ^ 1;
        const char* pA = pA0 + buf * 32768;
        const char* pB = pB0 + buf * 32768;

        // ---- phase 0: stage, vmcnt(2), barrier, read af0-3 + bf01, mfma m0-3 x n0-1
        STG(0, tnx, nbuf);
        asm volatile("s_waitcnt vmcnt(2)" ::: "memory");
        asm volatile("s_barrier" ::: "memory");
#pragma unroll
        for (int m = 0; m < 4; ++m) {
            af[m][0] = *(const s16x8*)(pA + m * 2048 + cLo);
            af[m][1] = *(const s16x8*)(pA + m * 2048 + cHi);
        }
#pragma unroll
        for (int n = 0; n < 2; ++n) {
            bf[n][0] = *(const s16x8*)(pB + n * 2048 + cLo);
            bf[n][1] = *(const s16x8*)(pB + n * 2048 + cHi);
        }
        asm volatile("s_waitcnt lgkmcnt(0)" ::: "memory");
        __builtin_amdgcn_sched_barrier(0);
        __builtin_amdgcn_s_setprio(1);
#pragma unroll
        for (int m = 0; m < 4; ++m)
#pragma unroll
            for (int n = 0; n < 2; ++n) {
                acc[m][n] = __builtin_amdgcn_mfma_f32_16x16x32_bf16(af[m][0], bf[n][0], acc[m][n], 0, 0, 0);
                acc[m][n] = __builtin_amdgcn_mfma_f32_16x16x32_bf16(af[m][1], bf[n][1], acc[m][n], 0, 0, 0);
            }
        __builtin_amdgcn_s_setprio(0);
        asm volatile("s_barrier" ::: "memory");

        // ---- phase 1: read bf(n2,n3), stage, barrier, mfma m0-3 x n2-3
#pragma unroll
        for (int n = 0; n < 2; ++n) {
            bf[n][0] = *(const s16x8*)(pB + (n + 2) * 2048 + cLo);
            bf[n][1] = *(const s16x8*)(pB + (n + 2) * 2048 + cHi);
        }
        STG(1, tnx, nbuf);
        asm volatile("s_barrier" ::: "memory");
        asm volatile("s_waitcnt lgkmcnt(0)" ::: "memory");
        __builtin_amdgcn_sched_barrier(0);
        __builtin_amdgcn_s_setprio(1);
#pragma unroll
        for (int m = 0; m < 4; ++m)
#pragma unroll
            for (int n = 0; n < 2; ++n) {
                acc[m][n + 2] = __builtin_amdgcn_mfma_f32_16x16x32_bf16(af[m][0], bf[n][0], acc[m][n + 2], 0, 0, 0);
                acc[m][n + 2] = __builtin_amdgcn_mfma_f32_16x16x32_bf16(af[m][1], bf[n][1], acc[m][n + 2], 0, 0, 0);
            }
        __builtin_amdgcn_s_setprio(0);
        asm volatile("s_barrier" ::: "memory");

        // ---- phase 2: read af(m4-7), stage, barrier, mfma m4-7 x n2-3
#pragma unroll
        for (int m = 0; m < 4; ++m) {
            af[m][0] = *(const s16x8*)(pA + (m + 4) * 2048 + cLo);
            af[m][1] = *(const s16x8*)(pA + (m + 4) * 2048 + cHi);
        }
        STG(2, tnx, nbuf);
        asm volatile("s_barrier" ::: "memory");
        asm volatile("s_waitcnt lgkmcnt(0)" ::: "memory");
        __builtin_amdgcn_sched_barrier(0);
        __builtin_amdgcn_s_setprio(1);
#pragma unroll
        for (int m = 0; m < 4; ++m)
#pragma unroll
            for (int n = 0; n < 2; ++n) {
                acc[m + 4][n + 2] = __builtin_amdgcn_mfma_f32_16x16x32_bf16(af[m][0], bf[n][0], acc[m + 4][n + 2], 0, 0, 0);
                acc[m + 4][n + 2] = __builtin_amdgcn_mfma_f32_16x16x32_bf16(af[m][1], bf[n][1], acc[m + 4][n + 2], 0, 0, 0);
            }
        __builtin_amdgcn_s_setprio(0);
        asm volatile("s_barrier" ::: "memory");

        // ---- phase 3: read bf(n0,n1), stage, barrier, mfma m4-7 x n0-1
#pragma unroll
        for (int n = 0; n < 2; ++n) {
            bf[n][0] = *(const s16x8*)(pB + n * 2048 + cLo);
            bf[n][1] = *(const s16x8*)(pB + n * 2048 + cHi);
        }
        STG(3, tnx, nbuf);
        asm volatile("s_barrier" ::: "memory");
        asm volatile("s_waitcnt lgkmcnt(0)" ::: "memory");
        __builtin_amdgcn_sched_barrier(0);
        __builtin_amdgcn_s_setprio(1);
#pragma unroll
        for (int m = 0; m < 4; ++m)
#pragma unroll
            for (int n = 0; n < 2; ++n) {
                acc[m + 4][n] = __builtin_amdgcn_mfma_f32_16x16x32_bf16(af[m][0], bf[n][0], acc[m + 4][n], 0, 0, 0);
                acc[m + 4][n] = __builtin_amdgcn_mfma_f32_16x16x32_bf16(af[m][1], bf[n][1], acc[m + 4][n], 0, 0, 0);
            }
        __builtin_amdgcn_s_setprio(0);
        asm volatile("s_barrier" ::: "memory");
    };

    for (int t = 0; t < NT; t += 2) {
        TILE(0, t + 1);
        TILE(1, (t + 2 < NT) ? (t + 2) : 0);   // last stage wraps (redundant, keeps vmcnt uniform)
    }

    // epilogue: C/D layout col=lane&15, row=(lane>>4)*4+j
    const int gcol0 = tn * 256 + wn * 64 + lrow;
    const int grow0 = tm * 256 + wm * 128 + (lane >> 4) * 4;
#pragma unroll
    for (int n = 0; n < 4; ++n) {
        float bv = bias[gcol0 + n * 16];
#pragma unroll
        for (int m = 0; m < 8; ++m) {
#pragma unroll
            for (int j = 0; j < 4; ++j) {
                unsigned short b = f32_to_bf16_bits(acc[m][n][j]);
                C[(size_t)(grow0 + m * 16 + j) * N + gcol0 + n * 16] =
                    __uint_as_float(((unsigned int)b) << 16) + bv;
            }
        }
    }
}

extern "C" void kernel_launch(void* const* d_in, const int* in_sizes, int n_in,
                              void* d_out, int out_size, void* d_ws, size_t ws_size,
                              hipStream_t stream) {
    const float* x    = (const float*)d_in[0];
    const float* w    = (const float*)d_in[1];
    const float* bias = (const float*)d_in[2];
    float* out = (float*)d_out;

    const int N = in_sizes[2];
    const long long KL = (long long)in_sizes[1] / N;
    const int K = (int)KL;
    const int M = (int)((long long)in_sizes[0] / KL);

    unsigned short* xq = (unsigned short*)d_ws;
    unsigned short* wq = xq + (size_t)M * K;

    long long n4 = (long long)M * K / 4;
    quant_x_kernel<<<(unsigned)((n4 + 255) / 256), 256, 0, stream>>>(x, xq, n4);

    dim3 gw(K / 64, N / 64);
    quant_w_kernel<<<gw, 256, 0, stream>>>(w, wq, N, K);

    const int nwg = (M / 256) * (N / 256);
    gemm8p<<<nwg, 512, 0, stream>>>(xq, wq, bias, out, M, N, K);
}